// Round 2
// baseline (117.263 us; speedup 1.0000x reference)
//
#include <hip/hip_runtime.h>
#include <math.h>

constexpr int H  = 4096;
constexpr int H2 = 8192;

// One wave64 per (row, half). half 0: columns [0,H) with z = h_prev (all gates).
// half 1: columns [H,2H) with z = x_t (f,i,o) and z = c_prev (C).
// 4 waves/block -> 2 rows/block -> 2048 blocks = 8 blocks/CU (32 waves/CU).
__global__ __launch_bounds__(256, 8)
void lstm_step_kernel(const float* __restrict__ h_prev,
                      const float* __restrict__ c_prev,
                      const float* __restrict__ x_t,
                      const float* __restrict__ W_f, const float* __restrict__ b_f,
                      const float* __restrict__ W_i, const float* __restrict__ b_i,
                      const float* __restrict__ W_C, const float* __restrict__ b_C,
                      const float* __restrict__ W_o, const float* __restrict__ b_o,
                      float* __restrict__ out)
{
    __shared__ float part[4][4];   // [wave][gate]

    const int wid  = threadIdx.x >> 6;          // 0..3
    const int lane = threadIdx.x & 63;
    const int row  = blockIdx.x * 2 + (wid >> 1);
    const int half = wid & 1;

    const size_t rowbase = (size_t)row * H2;
    const int hoff = half * 1024;               // float4 offset into the row
    const float4* wf = (const float4*)(W_f + rowbase) + hoff;
    const float4* wi = (const float4*)(W_i + rowbase) + hoff;
    const float4* wc = (const float4*)(W_C + rowbase) + hoff;
    const float4* wo = (const float4*)(W_o + rowbase) + hoff;
    const float4* hv = (const float4*)h_prev;
    const float4* xv = (const float4*)x_t;
    const float4* cv = (const float4*)c_prev;

    float4 af = make_float4(0.f, 0.f, 0.f, 0.f);
    float4 ai = make_float4(0.f, 0.f, 0.f, 0.f);
    float4 ac = make_float4(0.f, 0.f, 0.f, 0.f);
    float4 ao = make_float4(0.f, 0.f, 0.f, 0.f);

    if (half == 0) {
        #pragma unroll 8
        for (int it = 0; it < 16; ++it) {
            const int c = it * 64 + lane;       // 0..1023
            const float4 z = hv[c];
            const float4 a = wf[c];
            const float4 b = wi[c];
            const float4 d = wc[c];
            const float4 e = wo[c];
            af.x = fmaf(a.x, z.x, af.x); af.y = fmaf(a.y, z.y, af.y);
            af.z = fmaf(a.z, z.z, af.z); af.w = fmaf(a.w, z.w, af.w);
            ai.x = fmaf(b.x, z.x, ai.x); ai.y = fmaf(b.y, z.y, ai.y);
            ai.z = fmaf(b.z, z.z, ai.z); ai.w = fmaf(b.w, z.w, ai.w);
            ac.x = fmaf(d.x, z.x, ac.x); ac.y = fmaf(d.y, z.y, ac.y);
            ac.z = fmaf(d.z, z.z, ac.z); ac.w = fmaf(d.w, z.w, ac.w);
            ao.x = fmaf(e.x, z.x, ao.x); ao.y = fmaf(e.y, z.y, ao.y);
            ao.z = fmaf(e.z, z.z, ao.z); ao.w = fmaf(e.w, z.w, ao.w);
        }
    } else {
        #pragma unroll 8
        for (int it = 0; it < 16; ++it) {
            const int c = it * 64 + lane;       // 0..1023
            const float4 zx = xv[c];
            const float4 zc = cv[c];
            const float4 a = wf[c];
            const float4 b = wi[c];
            const float4 d = wc[c];
            const float4 e = wo[c];
            af.x = fmaf(a.x, zx.x, af.x); af.y = fmaf(a.y, zx.y, af.y);
            af.z = fmaf(a.z, zx.z, af.z); af.w = fmaf(a.w, zx.w, af.w);
            ai.x = fmaf(b.x, zx.x, ai.x); ai.y = fmaf(b.y, zx.y, ai.y);
            ai.z = fmaf(b.z, zx.z, ai.z); ai.w = fmaf(b.w, zx.w, ai.w);
            ac.x = fmaf(d.x, zc.x, ac.x); ac.y = fmaf(d.y, zc.y, ac.y);
            ac.z = fmaf(d.z, zc.z, ac.z); ac.w = fmaf(d.w, zc.w, ac.w);
            ao.x = fmaf(e.x, zx.x, ao.x); ao.y = fmaf(e.y, zx.y, ao.y);
            ao.z = fmaf(e.z, zx.z, ao.z); ao.w = fmaf(e.w, zx.w, ao.w);
        }
    }

    float sf = (af.x + af.y) + (af.z + af.w);
    float si = (ai.x + ai.y) + (ai.z + ai.w);
    float sc = (ac.x + ac.y) + (ac.z + ac.w);
    float so = (ao.x + ao.y) + (ao.z + ao.w);

    #pragma unroll
    for (int off = 32; off > 0; off >>= 1) {
        sf += __shfl_down(sf, off, 64);
        si += __shfl_down(si, off, 64);
        sc += __shfl_down(sc, off, 64);
        so += __shfl_down(so, off, 64);
    }

    if (lane == 0) {
        part[wid][0] = sf;
        part[wid][1] = si;
        part[wid][2] = sc;
        part[wid][3] = so;
    }
    __syncthreads();

    if (threadIdx.x < 2) {
        const int r  = blockIdx.x * 2 + (int)threadIdx.x;
        const int w0 = (int)threadIdx.x * 2;
        const float tf = part[w0][0] + part[w0 + 1][0];
        const float ti = part[w0][1] + part[w0 + 1][1];
        const float tc = part[w0][2] + part[w0 + 1][2];
        const float to = part[w0][3] + part[w0 + 1][3];

        const float f      = 1.f / (1.f + expf(-(tf + b_f[r])));
        const float ig     = 1.f / (1.f + expf(-(ti + b_i[r])));
        const float ctilde = tanhf(tc + b_C[r]);
        const float og     = 1.f / (1.f + expf(-(to + b_o[r])));
        const float Cnew   = f * c_prev[r] + ig * ctilde;
        out[r]     = og * tanhf(Cnew);     // h_t
        out[H + r] = Cnew;                 // C_t
    }
}

extern "C" void kernel_launch(void* const* d_in, const int* in_sizes, int n_in,
                              void* d_out, int out_size, void* d_ws, size_t ws_size,
                              hipStream_t stream) {
    const float* h_prev = (const float*)d_in[0];
    const float* c_prev = (const float*)d_in[1];
    const float* x_t    = (const float*)d_in[2];
    const float* W_f    = (const float*)d_in[3];
    const float* b_f    = (const float*)d_in[4];
    const float* W_i    = (const float*)d_in[5];
    const float* b_i    = (const float*)d_in[6];
    const float* W_C    = (const float*)d_in[7];
    const float* b_C    = (const float*)d_in[8];
    const float* W_o    = (const float*)d_in[9];
    const float* b_o    = (const float*)d_in[10];
    float* out = (float*)d_out;

    // 2 rows per block, 4096 rows -> 2048 blocks (= 8 blocks/CU on 256 CUs)
    lstm_step_kernel<<<H / 2, 256, 0, stream>>>(
        h_prev, c_prev, x_t, W_f, b_f, W_i, b_i, W_C, b_C, W_o, b_o, out);
}

// Round 4
// 96.321 us; speedup vs baseline: 1.2174x; 1.2174x over previous
//
#include <hip/hip_runtime.h>
#include <math.h>

constexpr int H  = 4096;
constexpr int H2 = 8192;

__device__ __forceinline__ void dot4(float4& acc, const float4 w, const float4 v) {
    acc.x = fmaf(w.x, v.x, acc.x);
    acc.y = fmaf(w.y, v.y, acc.y);
    acc.z = fmaf(w.z, v.z, acc.z);
    acc.w = fmaf(w.w, v.w, acc.w);
}

// One wave64 per output row; all four gate dot-products in one wave so the
// z-vector load is amortized 4x. Loads are manually hoisted in groups so
// ~15-20 global_load_dwordx4 stay in flight per wave (R1's VGPR=36 build
// kept only ~2 outstanding -> latency-bound at 2.8 TB/s HBM).
__global__ __launch_bounds__(256, 4)
void lstm_step_kernel(const float* __restrict__ h_prev,
                      const float* __restrict__ c_prev,
                      const float* __restrict__ x_t,
                      const float* __restrict__ W_f, const float* __restrict__ b_f,
                      const float* __restrict__ W_i, const float* __restrict__ b_i,
                      const float* __restrict__ W_C, const float* __restrict__ b_C,
                      const float* __restrict__ W_o, const float* __restrict__ b_o,
                      float* __restrict__ out)
{
    const int gtid = blockIdx.x * blockDim.x + threadIdx.x;
    const int row  = gtid >> 6;
    const int lane = threadIdx.x & 63;
    if (row >= H) return;

    const float4* wf = (const float4*)(W_f + (size_t)row * H2);
    const float4* wi = (const float4*)(W_i + (size_t)row * H2);
    const float4* wc = (const float4*)(W_C + (size_t)row * H2);
    const float4* wo = (const float4*)(W_o + (size_t)row * H2);
    const float4* hv = (const float4*)h_prev;
    const float4* xv = (const float4*)x_t;
    const float4* cv = (const float4*)c_prev;

    float4 af = make_float4(0.f, 0.f, 0.f, 0.f);
    float4 ai = make_float4(0.f, 0.f, 0.f, 0.f);
    float4 ac = make_float4(0.f, 0.f, 0.f, 0.f);
    float4 ao = make_float4(0.f, 0.f, 0.f, 0.f);

    // ---- half 0: columns [0,H), z = h_prev for all four gates ----
    // 16 chunks of 64 float4; groups of 4 chunks: issue all 20 loads
    // (chunk-major) before the first FMA so ~15 stay outstanding.
    for (int g = 0; g < 4; ++g) {
        const int c0 = g * 256 + lane;
        const int c1 = c0 + 64, c2 = c0 + 128, c3 = c0 + 192;
        const float4 z0 = hv[c0]; const float4 a0 = wf[c0]; const float4 b0 = wi[c0];
        const float4 d0 = wc[c0]; const float4 e0 = wo[c0];
        const float4 z1 = hv[c1]; const float4 a1 = wf[c1]; const float4 b1 = wi[c1];
        const float4 d1 = wc[c1]; const float4 e1 = wo[c1];
        const float4 z2 = hv[c2]; const float4 a2 = wf[c2]; const float4 b2 = wi[c2];
        const float4 d2 = wc[c2]; const float4 e2 = wo[c2];
        const float4 z3 = hv[c3]; const float4 a3 = wf[c3]; const float4 b3 = wi[c3];
        const float4 d3 = wc[c3]; const float4 e3 = wo[c3];
        dot4(af, a0, z0); dot4(ai, b0, z0); dot4(ac, d0, z0); dot4(ao, e0, z0);
        dot4(af, a1, z1); dot4(ai, b1, z1); dot4(ac, d1, z1); dot4(ao, e1, z1);
        dot4(af, a2, z2); dot4(ai, b2, z2); dot4(ac, d2, z2); dot4(ao, e2, z2);
        dot4(af, a3, z3); dot4(ai, b3, z3); dot4(ac, d3, z3); dot4(ao, e3, z3);
    }

    // ---- half 1: columns [H,2H), z = x_t for f,i,o ; z = c_prev for C ----
    // 6 loads per chunk -> groups of 2 to stay under the 128-VGPR cap.
    for (int g = 0; g < 8; ++g) {
        const int c0 = g * 128 + lane;
        const int c1 = c0 + 64;
        const int w0 = 1024 + c0, w1 = 1024 + c1;
        const float4 zx0 = xv[c0]; const float4 zc0 = cv[c0];
        const float4 a0 = wf[w0]; const float4 b0 = wi[w0];
        const float4 d0 = wc[w0]; const float4 e0 = wo[w0];
        const float4 zx1 = xv[c1]; const float4 zc1 = cv[c1];
        const float4 a1 = wf[w1]; const float4 b1 = wi[w1];
        const float4 d1 = wc[w1]; const float4 e1 = wo[w1];
        dot4(af, a0, zx0); dot4(ai, b0, zx0); dot4(ac, d0, zc0); dot4(ao, e0, zx0);
        dot4(af, a1, zx1); dot4(ai, b1, zx1); dot4(ac, d1, zc1); dot4(ao, e1, zx1);
    }

    float sf = (af.x + af.y) + (af.z + af.w);
    float si = (ai.x + ai.y) + (ai.z + ai.w);
    float sc = (ac.x + ac.y) + (ac.z + ac.w);
    float so = (ao.x + ao.y) + (ao.z + ao.w);

    #pragma unroll
    for (int off = 32; off > 0; off >>= 1) {
        sf += __shfl_down(sf, off, 64);
        si += __shfl_down(si, off, 64);
        sc += __shfl_down(sc, off, 64);
        so += __shfl_down(so, off, 64);
    }

    if (lane == 0) {
        const float f      = 1.f / (1.f + expf(-(sf + b_f[row])));
        const float ig     = 1.f / (1.f + expf(-(si + b_i[row])));
        const float ctilde = tanhf(sc + b_C[row]);
        const float og     = 1.f / (1.f + expf(-(so + b_o[row])));
        const float Cnew   = f * c_prev[row] + ig * ctilde;
        out[row]     = og * tanhf(Cnew);   // h_t
        out[H + row] = Cnew;               // C_t
    }
}

extern "C" void kernel_launch(void* const* d_in, const int* in_sizes, int n_in,
                              void* d_out, int out_size, void* d_ws, size_t ws_size,
                              hipStream_t stream) {
    const float* h_prev = (const float*)d_in[0];
    const float* c_prev = (const float*)d_in[1];
    const float* x_t    = (const float*)d_in[2];
    const float* W_f    = (const float*)d_in[3];
    const float* b_f    = (const float*)d_in[4];
    const float* W_i    = (const float*)d_in[5];
    const float* b_i    = (const float*)d_in[6];
    const float* W_C    = (const float*)d_in[7];
    const float* b_C    = (const float*)d_in[8];
    const float* W_o    = (const float*)d_in[9];
    const float* b_o    = (const float*)d_in[10];
    float* out = (float*)d_out;

    lstm_step_kernel<<<(H * 64) / 256, 256, 0, stream>>>(
        h_prev, c_prev, x_t, W_f, b_f, W_i, b_i, W_C, b_C, W_o, b_o, out);
}